// Round 1
// baseline (274.966 us; speedup 1.0000x reference)
//
#include <hip/hip_runtime.h>

#define NNODES 30000
#define NEDGES 480000
#define IN_DIM 256
#define OUT_DIM 256
#define HEADS 8
#define HEAD_DIM 32
#define NEG_SLOPE 0.2f
#define LN_EPS 1e-5f

// ---------------------------------------------------------------------------
// GEMM: h = x @ W   (M x 256) * (256 x 256), fp32, 64x64 tile, 4x4 microtile
// ---------------------------------------------------------------------------
__global__ __launch_bounds__(256) void gemm_kernel(const float* __restrict__ A,
                                                   const float* __restrict__ B,
                                                   float* __restrict__ C, int M) {
  const int K = IN_DIM, N = OUT_DIM;
  __shared__ float As[64][17];   // [m][k], +1 pad
  __shared__ float Bs[16][64];   // [k][n]

  const int t  = threadIdx.x;
  const int tx = t & 15;         // col group (4 cols each)
  const int ty = t >> 4;         // row group (4 rows each)
  const int row0 = blockIdx.y * 64;
  const int col0 = blockIdx.x * 64;

  float acc[4][4] = {};

  for (int kk = 0; kk < K; kk += 16) {
    // load A tile: thread t -> row t>>2, k-cols (t&3)*4 .. +4
    {
      int r = t >> 2, c = (t & 3) * 4;
      int gr = row0 + r;
      float4 v = make_float4(0.f, 0.f, 0.f, 0.f);
      if (gr < M) v = *(const float4*)&A[(size_t)gr * K + kk + c];
      As[r][c + 0] = v.x; As[r][c + 1] = v.y; As[r][c + 2] = v.z; As[r][c + 3] = v.w;
    }
    // load B tile: thread t -> row t>>4 (16 rows), cols (t&15)*4
    {
      int r = t >> 4, c = (t & 15) * 4;
      float4 v = *(const float4*)&B[(size_t)(kk + r) * N + col0 + c];
      *(float4*)&Bs[r][c] = v;
    }
    __syncthreads();
#pragma unroll
    for (int k = 0; k < 16; ++k) {
      float a0 = As[ty * 4 + 0][k];
      float a1 = As[ty * 4 + 1][k];
      float a2 = As[ty * 4 + 2][k];
      float a3 = As[ty * 4 + 3][k];
      float4 b = *(float4*)&Bs[k][tx * 4];
      acc[0][0] += a0 * b.x; acc[0][1] += a0 * b.y; acc[0][2] += a0 * b.z; acc[0][3] += a0 * b.w;
      acc[1][0] += a1 * b.x; acc[1][1] += a1 * b.y; acc[1][2] += a1 * b.z; acc[1][3] += a1 * b.w;
      acc[2][0] += a2 * b.x; acc[2][1] += a2 * b.y; acc[2][2] += a2 * b.z; acc[2][3] += a2 * b.w;
      acc[3][0] += a3 * b.x; acc[3][1] += a3 * b.y; acc[3][2] += a3 * b.z; acc[3][3] += a3 * b.w;
    }
    __syncthreads();
  }

#pragma unroll
  for (int i = 0; i < 4; ++i) {
    int gr = row0 + ty * 4 + i;
    if (gr < M) {
      float4 v = make_float4(acc[i][0], acc[i][1], acc[i][2], acc[i][3]);
      *(float4*)&C[(size_t)gr * N + col0 + tx * 4] = v;
    }
  }
}

// ---------------------------------------------------------------------------
// Per-(node,head) attention dots: a_src[n,h] = <h[n,h,:], att_src[h,:]>
// ---------------------------------------------------------------------------
__global__ __launch_bounds__(256) void attdots_kernel(const float* __restrict__ h,
                                                      const float* __restrict__ att_src,
                                                      const float* __restrict__ att_dst,
                                                      float* __restrict__ a_src,
                                                      float* __restrict__ a_dst,
                                                      int n_nodes) {
  int i = blockIdx.x * 256 + threadIdx.x;
  if (i >= n_nodes * HEADS) return;
  int n = i >> 3, hd = i & 7;
  const float4* hp = (const float4*)&h[(size_t)n * OUT_DIM + hd * HEAD_DIM];
  const float4* as = (const float4*)&att_src[hd * HEAD_DIM];
  const float4* ad = (const float4*)&att_dst[hd * HEAD_DIM];
  float s1 = 0.f, s2 = 0.f;
#pragma unroll
  for (int k = 0; k < HEAD_DIM / 4; ++k) {
    float4 v = hp[k], a = as[k], b = ad[k];
    s1 += v.x * a.x + v.y * a.y + v.z * a.z + v.w * a.w;
    s2 += v.x * b.x + v.y * b.y + v.z * b.z + v.w * b.w;
  }
  a_src[i] = s1;
  a_dst[i] = s2;
}

// ---------------------------------------------------------------------------
// CSR build
// ---------------------------------------------------------------------------
__global__ __launch_bounds__(256) void count_kernel(const int* __restrict__ ei,
                                                    int* __restrict__ counts, int E) {
  int e = blockIdx.x * 256 + threadIdx.x;
  if (e >= E) return;
  int dst = ei[E + e];
  atomicAdd(&counts[dst], 1);
}

__global__ __launch_bounds__(1024) void scan_kernel(const int* __restrict__ counts,
                                                    int* __restrict__ row_start,
                                                    int* __restrict__ cursor, int n) {
  __shared__ int buf[1024];
  __shared__ int carry_s;
  int tid = threadIdx.x;
  if (tid == 0) carry_s = 0;
  __syncthreads();
  for (int base = 0; base < n; base += 1024) {
    int i = base + tid;
    int v = (i < n) ? counts[i] : 0;
    buf[tid] = v;
    __syncthreads();
    for (int off = 1; off < 1024; off <<= 1) {
      int t2 = (tid >= off) ? buf[tid - off] : 0;
      __syncthreads();
      buf[tid] += t2;
      __syncthreads();
    }
    int excl = buf[tid] - v + carry_s;
    if (i < n) { row_start[i] = excl; cursor[i] = excl; }
    __syncthreads();
    if (tid == 1023) carry_s += buf[1023];
    __syncthreads();
  }
  if (tid == 0) row_start[n] = carry_s;
}

__global__ __launch_bounds__(256) void scatter_kernel(const int* __restrict__ ei,
                                                      int* __restrict__ cursor,
                                                      int* __restrict__ col_src, int E) {
  int e = blockIdx.x * 256 + threadIdx.x;
  if (e >= E) return;
  int s = ei[e];
  int d = ei[E + e];
  int pos = atomicAdd(&cursor[d], 1);
  col_src[pos] = s;
}

// ---------------------------------------------------------------------------
// Fused aggregate: per-node (one wave) segment softmax + weighted gather + LN
// lanes (phase1): slot = lane>>3 (8 edge slots), head1 = lane&7
// lanes (phase2): lane owns out dims [4*lane, 4*lane+4), head2 = lane>>3
// ---------------------------------------------------------------------------
__global__ __launch_bounds__(256) void aggregate_kernel(const float* __restrict__ h,
                                                        const float* __restrict__ a_src,
                                                        const float* __restrict__ a_dst,
                                                        const int* __restrict__ row_start,
                                                        const int* __restrict__ col_src,
                                                        const float* __restrict__ bias,
                                                        const float* __restrict__ gamma,
                                                        const float* __restrict__ beta,
                                                        float* __restrict__ out,
                                                        int n_nodes) {
  int node = blockIdx.x * 4 + (threadIdx.x >> 6);
  int lane = threadIdx.x & 63;
  if (node >= n_nodes) return;

  int beg = row_start[node];
  int end = row_start[node + 1];

  // ---- phase 1: per-head running max, then sum of exp ----
  int head1 = lane & 7;
  int slot  = lane >> 3;
  float adst1 = a_dst[node * HEADS + head1];
  float l_self = a_src[node * HEADS + head1] + adst1;
  l_self = (l_self > 0.f) ? l_self : NEG_SLOPE * l_self;

  float m = l_self;  // same value in all slots of a head: fine for max
  for (int e = beg + slot; e < end; e += 8) {
    int s = col_src[e];
    float l = a_src[s * HEADS + head1] + adst1;
    l = (l > 0.f) ? l : NEG_SLOPE * l;
    m = fmaxf(m, l);
  }
  m = fmaxf(m, __shfl_xor(m, 8));
  m = fmaxf(m, __shfl_xor(m, 16));
  m = fmaxf(m, __shfl_xor(m, 32));
  // m now = per-head max in every lane with head == lane&7

  float ssum = (slot == 0) ? __expf(l_self - m) : 0.f;
  for (int e = beg + slot; e < end; e += 8) {
    int s = col_src[e];
    float l = a_src[s * HEADS + head1] + adst1;
    l = (l > 0.f) ? l : NEG_SLOPE * l;
    ssum += __expf(l - m);
  }
  ssum += __shfl_xor(ssum, 8);
  ssum += __shfl_xor(ssum, 16);
  ssum += __shfl_xor(ssum, 32);

  // ---- phase 2: weighted gather ----
  int head2 = lane >> 3;
  float m2  = __shfl(m, head2);     // lane 'head2' holds head == head2
  float d2  = __shfl(ssum, head2);
  float inv = 1.f / d2;
  float adst2 = a_dst[node * HEADS + head2];

  float4 acc;
  {
    float l = a_src[node * HEADS + head2] + adst2;
    l = (l > 0.f) ? l : NEG_SLOPE * l;
    float w = __expf(l - m2) * inv;
    float4 hv = *(const float4*)&h[(size_t)node * OUT_DIM + lane * 4];
    acc.x = hv.x * w; acc.y = hv.y * w; acc.z = hv.z * w; acc.w = hv.w * w;
  }
  for (int e = beg; e < end; ++e) {
    int s = col_src[e];
    float l = a_src[s * HEADS + head2] + adst2;
    l = (l > 0.f) ? l : NEG_SLOPE * l;
    float w = __expf(l - m2) * inv;
    float4 hv = *(const float4*)&h[(size_t)s * OUT_DIM + lane * 4];
    acc.x += hv.x * w; acc.y += hv.y * w; acc.z += hv.z * w; acc.w += hv.w * w;
  }

  // ---- epilogue: + bias, LayerNorm, gamma/beta ----
  float4 b4 = *(const float4*)&bias[lane * 4];
  acc.x += b4.x; acc.y += b4.y; acc.z += b4.z; acc.w += b4.w;

  float s1 = acc.x + acc.y + acc.z + acc.w;
#pragma unroll
  for (int off = 1; off < 64; off <<= 1) s1 += __shfl_xor(s1, off);
  float mean = s1 * (1.f / OUT_DIM);

  float4 c = make_float4(acc.x - mean, acc.y - mean, acc.z - mean, acc.w - mean);
  float s2 = c.x * c.x + c.y * c.y + c.z * c.z + c.w * c.w;
#pragma unroll
  for (int off = 1; off < 64; off <<= 1) s2 += __shfl_xor(s2, off);
  float rstd = rsqrtf(s2 * (1.f / OUT_DIM) + LN_EPS);

  float4 g4 = *(const float4*)&gamma[lane * 4];
  float4 e4 = *(const float4*)&beta[lane * 4];
  float4 o;
  o.x = c.x * rstd * g4.x + e4.x;
  o.y = c.y * rstd * g4.y + e4.y;
  o.z = c.z * rstd * g4.z + e4.z;
  o.w = c.w * rstd * g4.w + e4.w;
  *(float4*)&out[(size_t)node * OUT_DIM + lane * 4] = o;
}

// ---------------------------------------------------------------------------
extern "C" void kernel_launch(void* const* d_in, const int* in_sizes, int n_in,
                              void* d_out, int out_size, void* d_ws, size_t ws_size,
                              hipStream_t stream) {
  const float* x       = (const float*)d_in[0];
  const int*   ei      = (const int*)d_in[1];
  const float* W       = (const float*)d_in[2];
  const float* att_src = (const float*)d_in[3];
  const float* att_dst = (const float*)d_in[4];
  const float* bias    = (const float*)d_in[5];
  const float* gamma   = (const float*)d_in[6];
  const float* beta    = (const float*)d_in[7];
  float* out = (float*)d_out;

  const int M = in_sizes[0] / IN_DIM;       // 30000
  const int E = in_sizes[1] / 2;            // 480000

  // workspace carve (256B aligned)
  char* w = (char*)d_ws;
  auto carve = [&](size_t bytes) {
    char* p = w;
    w += (bytes + 255) & ~(size_t)255;
    return p;
  };
  float* h       = (float*)carve((size_t)M * OUT_DIM * 4);
  float* a_src   = (float*)carve((size_t)M * HEADS * 4);
  float* a_dst   = (float*)carve((size_t)M * HEADS * 4);
  int*   row_st  = (int*)carve((size_t)(M + 1) * 4);
  int*   cursor  = (int*)carve((size_t)M * 4);
  int*   counts  = (int*)carve((size_t)M * 4);
  int*   col_src = (int*)carve((size_t)E * 4);

  hipMemsetAsync(counts, 0, (size_t)M * 4, stream);

  dim3 ggrid(OUT_DIM / 64, (M + 63) / 64);
  gemm_kernel<<<ggrid, 256, 0, stream>>>(x, W, h, M);

  attdots_kernel<<<(M * HEADS + 255) / 256, 256, 0, stream>>>(h, att_src, att_dst, a_src, a_dst, M);

  count_kernel<<<(E + 255) / 256, 256, 0, stream>>>(ei, counts, E);
  scan_kernel<<<1, 1024, 0, stream>>>(counts, row_st, cursor, M);
  scatter_kernel<<<(E + 255) / 256, 256, 0, stream>>>(ei, cursor, col_src, E);

  aggregate_kernel<<<(M + 3) / 4, 256, 0, stream>>>(h, a_src, a_dst, row_st, col_src,
                                                    bias, gamma, beta, out, M);
}

// Round 2
// 210.406 us; speedup vs baseline: 1.3068x; 1.3068x over previous
//
#include <hip/hip_runtime.h>

#define IN_DIM 256
#define OUT_DIM 256
#define HEADS 8
#define HEAD_DIM 32
#define NEG_SLOPE 0.2f
#define LN_EPS 1e-5f

typedef __attribute__((ext_vector_type(8))) short bf16x8;
typedef __attribute__((ext_vector_type(4))) float f32x4;
typedef __attribute__((ext_vector_type(4))) unsigned short us4;
typedef __attribute__((ext_vector_type(8))) unsigned short us8;

__device__ inline unsigned short f2b(float f) {
  unsigned u = __float_as_uint(f);
  u += 0x7FFF + ((u >> 16) & 1);   // round-to-nearest-even
  return (unsigned short)(u >> 16);
}
__device__ inline float b2f(unsigned short u) {
  return __uint_as_float(((unsigned)u) << 16);
}

// ---------------------------------------------------------------------------
// fp32 -> bf16 conversion of x (8 elems / thread)
// ---------------------------------------------------------------------------
__global__ __launch_bounds__(256) void convert_x(const float* __restrict__ x,
                                                 unsigned short* __restrict__ xb, int n8) {
  int i = blockIdx.x * 256 + threadIdx.x;
  if (i >= n8) return;
  const float4* p = (const float4*)(x + (size_t)i * 8);
  float4 v0 = p[0], v1 = p[1];
  us8 o;
  o[0] = f2b(v0.x); o[1] = f2b(v0.y); o[2] = f2b(v0.z); o[3] = f2b(v0.w);
  o[4] = f2b(v1.x); o[5] = f2b(v1.y); o[6] = f2b(v1.z); o[7] = f2b(v1.w);
  *(us8*)&xb[(size_t)i * 8] = o;
}

// W [k][n] fp32 -> Wt [n][k] bf16
__global__ __launch_bounds__(256) void convert_wt(const float* __restrict__ W,
                                                  unsigned short* __restrict__ Wt) {
  int i = blockIdx.x * 256 + threadIdx.x;   // i = k*256 + n (coalesced read)
  int k = i >> 8, n = i & 255;
  Wt[n * 256 + k] = f2b(W[i]);
}

// ---------------------------------------------------------------------------
// GEMM: hb = xb @ W  via bf16 MFMA. 128x128 tile, BK=32, 4 waves, 4x4 frags.
// ---------------------------------------------------------------------------
#define BM 128
#define BN 128
#define BK 32

__global__ __launch_bounds__(256) void gemm_bf16(const unsigned short* __restrict__ A,
                                                 const unsigned short* __restrict__ Bt,
                                                 unsigned short* __restrict__ C, int M) {
  __shared__ unsigned short As[BM][BK + 8];   // [m][k], row stride 80B (16B-aligned)
  __shared__ unsigned short Bs[BN][BK + 8];   // [n][k]

  const int t = threadIdx.x;
  const int lane = t & 63, wid = t >> 6;
  const int wm = wid >> 1, wn = wid & 1;
  const int row0 = blockIdx.y * BM, col0 = blockIdx.x * BN;
  const int lr = lane & 15, lk = lane >> 4;

  f32x4 acc[4][4] = {};

  for (int kk = 0; kk < IN_DIM; kk += BK) {
    __syncthreads();
#pragma unroll
    for (int c = t; c < 512; c += 256) {       // A tile: 128 rows x 4 chunks of 16B
      int r = c >> 2, off = (c & 3) * 8;
      int gr = row0 + r;
      us8 v = {0, 0, 0, 0, 0, 0, 0, 0};
      if (gr < M) v = *(const us8*)&A[(size_t)gr * IN_DIM + kk + off];
      *(us8*)&As[r][off] = v;
    }
#pragma unroll
    for (int c = t; c < 512; c += 256) {       // B tile
      int r = c >> 2, off = (c & 3) * 8;
      us8 v = *(const us8*)&Bt[(size_t)(col0 + r) * IN_DIM + kk + off];
      *(us8*)&Bs[r][off] = v;
    }
    __syncthreads();

    bf16x8 af[4], bfr[4];
#pragma unroll
    for (int i = 0; i < 4; ++i)
      af[i] = *(bf16x8*)&As[wm * 64 + i * 16 + lr][lk * 8];
#pragma unroll
    for (int i = 0; i < 4; ++i)
      bfr[i] = *(bf16x8*)&Bs[wn * 64 + i * 16 + lr][lk * 8];
#pragma unroll
    for (int i = 0; i < 4; ++i)
#pragma unroll
      for (int j = 0; j < 4; ++j)
        acc[i][j] = __builtin_amdgcn_mfma_f32_16x16x32_bf16(af[i], bfr[j], acc[i][j], 0, 0, 0);
  }

#pragma unroll
  for (int i = 0; i < 4; ++i) {
#pragma unroll
    for (int q = 0; q < 4; ++q) {
      int row = row0 + wm * 64 + i * 16 + (lane >> 4) * 4 + q;
      if (row < M) {
#pragma unroll
        for (int j = 0; j < 4; ++j) {
          int col = col0 + wn * 64 + j * 16 + lr;
          C[(size_t)row * OUT_DIM + col] = f2b(acc[i][j][q]);
        }
      }
    }
  }
}

// ---------------------------------------------------------------------------
// a_src[n,h] = <hb[n,h,:], att_src[h,:]>, a_dst likewise  (bf16 h)
// ---------------------------------------------------------------------------
__global__ __launch_bounds__(256) void attdots_kernel(const unsigned short* __restrict__ hb,
                                                      const float* __restrict__ att_src,
                                                      const float* __restrict__ att_dst,
                                                      float* __restrict__ a_src,
                                                      float* __restrict__ a_dst, int M) {
  int i = blockIdx.x * 256 + threadIdx.x;
  if (i >= M * HEADS) return;
  int hd = i & 7;
  const unsigned short* hp = hb + (size_t)i * HEAD_DIM;
  const float* as = att_src + hd * HEAD_DIM;
  const float* ad = att_dst + hd * HEAD_DIM;
  float s1 = 0.f, s2 = 0.f;
#pragma unroll
  for (int k0 = 0; k0 < HEAD_DIM; k0 += 8) {
    us8 v = *(const us8*)&hp[k0];
#pragma unroll
    for (int j = 0; j < 8; ++j) {
      float f = b2f(v[j]);
      s1 += f * as[k0 + j];
      s2 += f * ad[k0 + j];
    }
  }
  a_src[i] = s1;
  a_dst[i] = s2;
}

// ---------------------------------------------------------------------------
// CSR build
// ---------------------------------------------------------------------------
__global__ __launch_bounds__(256) void count_kernel(const int* __restrict__ ei,
                                                    int* __restrict__ counts, int E) {
  int e = blockIdx.x * 256 + threadIdx.x;
  if (e >= E) return;
  atomicAdd(&counts[ei[E + e]], 1);
}

// single-block, single-pass scan: each thread owns ceil(n/1024) contiguous items
__global__ __launch_bounds__(1024) void scan_kernel(const int* __restrict__ counts,
                                                    int* __restrict__ row_start,
                                                    int* __restrict__ cursor, int n) {
  __shared__ int wsum[16];
  __shared__ int wexcl[16];
  int t = threadIdx.x;
  int lane = t & 63, wid = t >> 6;
  int items = (n + 1023) >> 10;
  int base = t * items;

  int s = 0;
  for (int i = 0; i < items; ++i) {
    int idx = base + i;
    if (idx < n) s += counts[idx];
  }
  int incl = s;
#pragma unroll
  for (int off = 1; off < 64; off <<= 1) {
    int o = __shfl_up(incl, off);
    if (lane >= off) incl += o;
  }
  if (lane == 63) wsum[wid] = incl;
  __syncthreads();
  if (wid == 0) {
    int v = (lane < 16) ? wsum[lane] : 0;
    int iv = v;
#pragma unroll
    for (int off = 1; off < 16; off <<= 1) {
      int o = __shfl_up(iv, off);
      if (lane >= off) iv += o;
    }
    if (lane < 16) wexcl[lane] = iv - v;
  }
  __syncthreads();
  int excl = wexcl[wid] + incl - s;
  int run = excl;
  for (int i = 0; i < items; ++i) {
    int idx = base + i;
    if (idx < n) {
      row_start[idx] = run;
      cursor[idx] = run;
      run += counts[idx];
    }
  }
  if (t == 1023) row_start[n] = excl;   // all of t=1023's items are OOB -> excl == total
}

__global__ __launch_bounds__(256) void scatter_kernel(const int* __restrict__ ei,
                                                      int* __restrict__ cursor,
                                                      int* __restrict__ col_src, int E) {
  int e = blockIdx.x * 256 + threadIdx.x;
  if (e >= E) return;
  int s = ei[e];
  int d = ei[E + e];
  int pos = atomicAdd(&cursor[d], 1);
  col_src[pos] = s;
}

// ---------------------------------------------------------------------------
// Fused aggregate: one wave per node; segment softmax + bf16 gather + LN
// ---------------------------------------------------------------------------
__global__ __launch_bounds__(256) void aggregate_kernel(const unsigned short* __restrict__ hb,
                                                        const float* __restrict__ a_src,
                                                        const float* __restrict__ a_dst,
                                                        const int* __restrict__ row_start,
                                                        const int* __restrict__ col_src,
                                                        const float* __restrict__ bias,
                                                        const float* __restrict__ gamma,
                                                        const float* __restrict__ beta,
                                                        float* __restrict__ out, int n_nodes) {
  int node = blockIdx.x * 4 + (threadIdx.x >> 6);
  int lane = threadIdx.x & 63;
  if (node >= n_nodes) return;

  int beg = row_start[node];
  int end = row_start[node + 1];

  // ---- phase 1: per-head max then sum-of-exp (lanes = 8 slots x 8 heads) ----
  int head1 = lane & 7;
  int slot = lane >> 3;
  float adst1 = a_dst[node * HEADS + head1];
  float l_self = a_src[node * HEADS + head1] + adst1;
  l_self = (l_self > 0.f) ? l_self : NEG_SLOPE * l_self;

  float m = l_self;
  for (int e = beg + slot; e < end; e += 8) {
    int s = col_src[e];
    float l = a_src[s * HEADS + head1] + adst1;
    l = (l > 0.f) ? l : NEG_SLOPE * l;
    m = fmaxf(m, l);
  }
  m = fmaxf(m, __shfl_xor(m, 8));
  m = fmaxf(m, __shfl_xor(m, 16));
  m = fmaxf(m, __shfl_xor(m, 32));

  float ssum = (slot == 0) ? __expf(l_self - m) : 0.f;
  for (int e = beg + slot; e < end; e += 8) {
    int s = col_src[e];
    float l = a_src[s * HEADS + head1] + adst1;
    l = (l > 0.f) ? l : NEG_SLOPE * l;
    ssum += __expf(l - m);
  }
  ssum += __shfl_xor(ssum, 8);
  ssum += __shfl_xor(ssum, 16);
  ssum += __shfl_xor(ssum, 32);

  // ---- phase 2: weighted bf16 gather (lane owns dims [4*lane,4*lane+4)) ----
  int head2 = lane >> 3;
  float m2 = __shfl(m, head2);
  float inv = 1.f / __shfl(ssum, head2);
  float adst2 = a_dst[node * HEADS + head2];

  auto ew = [&](int s) -> float {
    float l = a_src[s * HEADS + head2] + adst2;
    l = (l > 0.f) ? l : NEG_SLOPE * l;
    return __expf(l - m2);
  };

  float4 acc;
  {
    float w = ew(node);
    us4 hv = *(const us4*)&hb[(size_t)node * OUT_DIM + lane * 4];
    acc.x = w * b2f(hv[0]); acc.y = w * b2f(hv[1]);
    acc.z = w * b2f(hv[2]); acc.w = w * b2f(hv[3]);
  }
  int e = beg;
  for (; e + 4 <= end; e += 4) {
    int s0 = col_src[e], s1 = col_src[e + 1], s2 = col_src[e + 2], s3 = col_src[e + 3];
    float w0 = ew(s0), w1 = ew(s1), w2 = ew(s2), w3 = ew(s3);
    us4 v0 = *(const us4*)&hb[(size_t)s0 * OUT_DIM + lane * 4];
    us4 v1 = *(const us4*)&hb[(size_t)s1 * OUT_DIM + lane * 4];
    us4 v2 = *(const us4*)&hb[(size_t)s2 * OUT_DIM + lane * 4];
    us4 v3 = *(const us4*)&hb[(size_t)s3 * OUT_DIM + lane * 4];
    acc.x += w0 * b2f(v0[0]) + w1 * b2f(v1[0]) + w2 * b2f(v2[0]) + w3 * b2f(v3[0]);
    acc.y += w0 * b2f(v0[1]) + w1 * b2f(v1[1]) + w2 * b2f(v2[1]) + w3 * b2f(v3[1]);
    acc.z += w0 * b2f(v0[2]) + w1 * b2f(v1[2]) + w2 * b2f(v2[2]) + w3 * b2f(v3[2]);
    acc.w += w0 * b2f(v0[3]) + w1 * b2f(v1[3]) + w2 * b2f(v2[3]) + w3 * b2f(v3[3]);
  }
  for (; e < end; ++e) {
    int s = col_src[e];
    float w = ew(s);
    us4 hv = *(const us4*)&hb[(size_t)s * OUT_DIM + lane * 4];
    acc.x += w * b2f(hv[0]); acc.y += w * b2f(hv[1]);
    acc.z += w * b2f(hv[2]); acc.w += w * b2f(hv[3]);
  }
  acc.x *= inv; acc.y *= inv; acc.z *= inv; acc.w *= inv;

  // ---- epilogue: + bias, LayerNorm, gamma/beta ----
  float4 b4 = *(const float4*)&bias[lane * 4];
  acc.x += b4.x; acc.y += b4.y; acc.z += b4.z; acc.w += b4.w;

  float s1 = acc.x + acc.y + acc.z + acc.w;
#pragma unroll
  for (int off = 1; off < 64; off <<= 1) s1 += __shfl_xor(s1, off);
  float mean = s1 * (1.f / OUT_DIM);

  float4 c = make_float4(acc.x - mean, acc.y - mean, acc.z - mean, acc.w - mean);
  float s2 = c.x * c.x + c.y * c.y + c.z * c.z + c.w * c.w;
#pragma unroll
  for (int off = 1; off < 64; off <<= 1) s2 += __shfl_xor(s2, off);
  float rstd = rsqrtf(s2 * (1.f / OUT_DIM) + LN_EPS);

  float4 g4 = *(const float4*)&gamma[lane * 4];
  float4 e4 = *(const float4*)&beta[lane * 4];
  float4 o;
  o.x = c.x * rstd * g4.x + e4.x;
  o.y = c.y * rstd * g4.y + e4.y;
  o.z = c.z * rstd * g4.z + e4.z;
  o.w = c.w * rstd * g4.w + e4.w;
  *(float4*)&out[(size_t)node * OUT_DIM + lane * 4] = o;
}

// ---------------------------------------------------------------------------
extern "C" void kernel_launch(void* const* d_in, const int* in_sizes, int n_in,
                              void* d_out, int out_size, void* d_ws, size_t ws_size,
                              hipStream_t stream) {
  const float* x       = (const float*)d_in[0];
  const int*   ei      = (const int*)d_in[1];
  const float* W       = (const float*)d_in[2];
  const float* att_src = (const float*)d_in[3];
  const float* att_dst = (const float*)d_in[4];
  const float* bias    = (const float*)d_in[5];
  const float* gamma   = (const float*)d_in[6];
  const float* beta    = (const float*)d_in[7];
  float* out = (float*)d_out;

  const int M = in_sizes[0] / IN_DIM;   // 30000
  const int E = in_sizes[1] / 2;        // 480000

  char* w = (char*)d_ws;
  auto carve = [&](size_t bytes) {
    char* p = w;
    w += (bytes + 255) & ~(size_t)255;
    return p;
  };
  unsigned short* xb  = (unsigned short*)carve((size_t)M * IN_DIM * 2);
  unsigned short* Wt  = (unsigned short*)carve((size_t)IN_DIM * OUT_DIM * 2);
  unsigned short* hb  = (unsigned short*)carve((size_t)M * OUT_DIM * 2);
  float* a_srcP = (float*)carve((size_t)M * HEADS * 4);
  float* a_dstP = (float*)carve((size_t)M * HEADS * 4);
  int* row_st   = (int*)carve((size_t)(M + 1) * 4);
  int* cursor   = (int*)carve((size_t)M * 4);
  int* counts   = (int*)carve((size_t)M * 4);
  int* col_src  = (int*)carve((size_t)E * 4);

  hipMemsetAsync(counts, 0, (size_t)M * 4, stream);

  convert_x<<<(M * (IN_DIM / 8) + 255) / 256, 256, 0, stream>>>(x, xb, M * (IN_DIM / 8));
  convert_wt<<<(IN_DIM * OUT_DIM) / 256, 256, 0, stream>>>(W, Wt);
  count_kernel<<<(E + 255) / 256, 256, 0, stream>>>(ei, counts, E);

  gemm_bf16<<<dim3(OUT_DIM / BN, (M + BM - 1) / BM), 256, 0, stream>>>(xb, Wt, hb, M);

  attdots_kernel<<<(M * HEADS + 255) / 256, 256, 0, stream>>>(hb, att_src, att_dst,
                                                              a_srcP, a_dstP, M);
  scan_kernel<<<1, 1024, 0, stream>>>(counts, row_st, cursor, M);
  scatter_kernel<<<(E + 255) / 256, 256, 0, stream>>>(ei, cursor, col_src, E);

  aggregate_kernel<<<(M + 3) / 4, 256, 0, stream>>>(hb, a_srcP, a_dstP, row_st, col_src,
                                                    bias, gamma, beta, out, M);
}

// Round 3
// 148.913 us; speedup vs baseline: 1.8465x; 1.4129x over previous
//
#include <hip/hip_runtime.h>

#define IN_DIM 256
#define OUT_DIM 256
#define HEADS 8
#define HEAD_DIM 32
#define NEG_SLOPE 0.2f
#define LN_EPS 1e-5f

typedef __attribute__((ext_vector_type(8))) short bf16x8;
typedef __attribute__((ext_vector_type(4))) float f32x4;
typedef __attribute__((ext_vector_type(4))) unsigned short us4;
typedef __attribute__((ext_vector_type(8))) unsigned short us8;

__device__ inline unsigned short f2b(float f) {
  unsigned u = __float_as_uint(f);
  u += 0x7FFF + ((u >> 16) & 1);   // round-to-nearest-even
  return (unsigned short)(u >> 16);
}
__device__ inline float b2f(unsigned short u) {
  return __uint_as_float(((unsigned)u) << 16);
}

// ---------------------------------------------------------------------------
// fp32 -> bf16 conversion of x (8 elems / thread)
// ---------------------------------------------------------------------------
__global__ __launch_bounds__(256) void convert_x(const float* __restrict__ x,
                                                 unsigned short* __restrict__ xb, int n8) {
  int i = blockIdx.x * 256 + threadIdx.x;
  if (i >= n8) return;
  const float4* p = (const float4*)(x + (size_t)i * 8);
  float4 v0 = p[0], v1 = p[1];
  us8 o;
  o[0] = f2b(v0.x); o[1] = f2b(v0.y); o[2] = f2b(v0.z); o[3] = f2b(v0.w);
  o[4] = f2b(v1.x); o[5] = f2b(v1.y); o[6] = f2b(v1.z); o[7] = f2b(v1.w);
  *(us8*)&xb[(size_t)i * 8] = o;
}

// W [k][n] fp32 -> Wt [n][k] bf16
__global__ __launch_bounds__(256) void convert_wt(const float* __restrict__ W,
                                                  unsigned short* __restrict__ Wt) {
  int i = blockIdx.x * 256 + threadIdx.x;   // i = k*256 + n (coalesced read)
  int k = i >> 8, n = i & 255;
  Wt[n * 256 + k] = f2b(W[i]);
}

// ---------------------------------------------------------------------------
// GEMM: hb = xb @ W  via bf16 MFMA. 128x128 tile, BK=32, 4 waves, 4x4 frags.
// ---------------------------------------------------------------------------
#define BM 128
#define BN 128
#define BK 32

__global__ __launch_bounds__(256) void gemm_bf16(const unsigned short* __restrict__ A,
                                                 const unsigned short* __restrict__ Bt,
                                                 unsigned short* __restrict__ C, int M) {
  __shared__ unsigned short As[BM][BK + 8];   // [m][k]
  __shared__ unsigned short Bs[BN][BK + 8];   // [n][k]

  const int t = threadIdx.x;
  const int lane = t & 63, wid = t >> 6;
  const int wm = wid >> 1, wn = wid & 1;
  const int row0 = blockIdx.y * BM, col0 = blockIdx.x * BN;
  const int lr = lane & 15, lk = lane >> 4;

  f32x4 acc[4][4] = {};

  for (int kk = 0; kk < IN_DIM; kk += BK) {
    __syncthreads();
#pragma unroll
    for (int c = t; c < 512; c += 256) {       // A tile
      int r = c >> 2, off = (c & 3) * 8;
      int gr = row0 + r;
      us8 v = {0, 0, 0, 0, 0, 0, 0, 0};
      if (gr < M) v = *(const us8*)&A[(size_t)gr * IN_DIM + kk + off];
      *(us8*)&As[r][off] = v;
    }
#pragma unroll
    for (int c = t; c < 512; c += 256) {       // B tile
      int r = c >> 2, off = (c & 3) * 8;
      us8 v = *(const us8*)&Bt[(size_t)(col0 + r) * IN_DIM + kk + off];
      *(us8*)&Bs[r][off] = v;
    }
    __syncthreads();

    bf16x8 af[4], bfr[4];
#pragma unroll
    for (int i = 0; i < 4; ++i)
      af[i] = *(bf16x8*)&As[wm * 64 + i * 16 + lr][lk * 8];
#pragma unroll
    for (int i = 0; i < 4; ++i)
      bfr[i] = *(bf16x8*)&Bs[wn * 64 + i * 16 + lr][lk * 8];
#pragma unroll
    for (int i = 0; i < 4; ++i)
#pragma unroll
      for (int j = 0; j < 4; ++j)
        acc[i][j] = __builtin_amdgcn_mfma_f32_16x16x32_bf16(af[i], bfr[j], acc[i][j], 0, 0, 0);
  }

#pragma unroll
  for (int i = 0; i < 4; ++i) {
#pragma unroll
    for (int q = 0; q < 4; ++q) {
      int row = row0 + wm * 64 + i * 16 + (lane >> 4) * 4 + q;
      if (row < M) {
#pragma unroll
        for (int j = 0; j < 4; ++j) {
          int col = col0 + wn * 64 + j * 16 + lr;
          C[(size_t)row * OUT_DIM + col] = f2b(acc[i][j][q]);
        }
      }
    }
  }
}

// ---------------------------------------------------------------------------
// a_src[n,h] = <hb[n,h,:], att_src[h,:]>, a_dst likewise  (bf16 h)
// ---------------------------------------------------------------------------
__global__ __launch_bounds__(256) void attdots_kernel(const unsigned short* __restrict__ hb,
                                                      const float* __restrict__ att_src,
                                                      const float* __restrict__ att_dst,
                                                      float* __restrict__ a_src,
                                                      float* __restrict__ a_dst, int M) {
  int i = blockIdx.x * 256 + threadIdx.x;
  if (i >= M * HEADS) return;
  int hd = i & 7;
  const unsigned short* hp = hb + (size_t)i * HEAD_DIM;
  const float* as = att_src + hd * HEAD_DIM;
  const float* ad = att_dst + hd * HEAD_DIM;
  float s1 = 0.f, s2 = 0.f;
#pragma unroll
  for (int k0 = 0; k0 < HEAD_DIM; k0 += 8) {
    us8 v = *(const us8*)&hp[k0];
#pragma unroll
    for (int j = 0; j < 8; ++j) {
      float f = b2f(v[j]);
      s1 += f * as[k0 + j];
      s2 += f * ad[k0 + j];
    }
  }
  a_src[i] = s1;
  a_dst[i] = s2;
}

// ---------------------------------------------------------------------------
// CSR build: count -> 3-stage decoupled scan -> scatter
// ---------------------------------------------------------------------------
__global__ __launch_bounds__(256) void count_kernel(const int* __restrict__ ei,
                                                    int* __restrict__ counts, int E) {
  int e = blockIdx.x * 256 + threadIdx.x;
  if (e >= E) return;
  atomicAdd(&counts[ei[E + e]], 1);
}

__global__ __launch_bounds__(256) void block_sums(const int* __restrict__ counts,
                                                  int* __restrict__ bsum, int n) {
  int i = blockIdx.x * 256 + threadIdx.x;
  int lane = threadIdx.x & 63, wid = threadIdx.x >> 6;
  int v = (i < n) ? counts[i] : 0;
#pragma unroll
  for (int off = 1; off < 64; off <<= 1) v += __shfl_xor(v, off);
  __shared__ int ws[4];
  if (lane == 0) ws[wid] = v;
  __syncthreads();
  if (threadIdx.x == 0) bsum[blockIdx.x] = ws[0] + ws[1] + ws[2] + ws[3];
}

// nb <= 128
__global__ __launch_bounds__(128) void scan_sums(const int* __restrict__ bsum,
                                                 int* __restrict__ bofs,
                                                 int* __restrict__ row_start,
                                                 int nb, int n) {
  int t = threadIdx.x, lane = t & 63, wid = t >> 6;
  int v = (t < nb) ? bsum[t] : 0;
  int incl = v;
#pragma unroll
  for (int off = 1; off < 64; off <<= 1) {
    int o = __shfl_up(incl, off);
    if (lane >= off) incl += o;
  }
  __shared__ int ws[2];
  if (lane == 63) ws[wid] = incl;
  __syncthreads();
  if (wid == 1) incl += ws[0];
  if (t < nb) bofs[t] = incl - v;
  if (t == nb - 1) row_start[n] = incl;
}

__global__ __launch_bounds__(256) void scan_final(const int* __restrict__ counts,
                                                  const int* __restrict__ bofs,
                                                  int* __restrict__ row_start,
                                                  int* __restrict__ cursor, int n) {
  int i = blockIdx.x * 256 + threadIdx.x;
  int lane = threadIdx.x & 63, wid = threadIdx.x >> 6;
  int v = (i < n) ? counts[i] : 0;
  int incl = v;
#pragma unroll
  for (int off = 1; off < 64; off <<= 1) {
    int o = __shfl_up(incl, off);
    if (lane >= off) incl += o;
  }
  __shared__ int ws[4];
  if (lane == 63) ws[wid] = incl;
  __syncthreads();
  int wadd = 0;
#pragma unroll
  for (int j = 0; j < 4; ++j)
    if (j < wid) wadd += ws[j];
  int excl = bofs[blockIdx.x] + wadd + incl - v;
  if (i < n) { row_start[i] = excl; cursor[i] = excl; }
}

__global__ __launch_bounds__(256) void scatter_kernel(const int* __restrict__ ei,
                                                      int* __restrict__ cursor,
                                                      int* __restrict__ col_src, int E) {
  int e = blockIdx.x * 256 + threadIdx.x;
  if (e >= E) return;
  int s = ei[e];
  int d = ei[E + e];
  int pos = atomicAdd(&cursor[d], 1);
  col_src[pos] = s;
}

// ---------------------------------------------------------------------------
// Fused aggregate: one wave per node; online segment softmax + bf16 gather + LN
// ---------------------------------------------------------------------------
__global__ __launch_bounds__(256) void aggregate_kernel(const unsigned short* __restrict__ hb,
                                                        const float* __restrict__ a_src,
                                                        const float* __restrict__ a_dst,
                                                        const int* __restrict__ row_start,
                                                        const int* __restrict__ col_src,
                                                        const float* __restrict__ bias,
                                                        const float* __restrict__ gamma,
                                                        const float* __restrict__ beta,
                                                        float* __restrict__ out, int n_nodes) {
  int node = blockIdx.x * 4 + (threadIdx.x >> 6);
  int lane = threadIdx.x & 63;
  if (node >= n_nodes) return;

  int beg = row_start[node];
  int end = row_start[node + 1];

  // ---- phase 1: online per-head (max, sum-of-exp); lanes = 8 slots x 8 heads
  int head1 = lane & 7;
  int slot = lane >> 3;
  float adst1 = a_dst[node * HEADS + head1];
  float l_self = a_src[node * HEADS + head1] + adst1;
  l_self = (l_self > 0.f) ? l_self : NEG_SLOPE * l_self;

  float m = l_self;                         // self-logit is in the set for all lanes: safe as max seed
  float ssum = (slot == 0) ? 1.0f : 0.f;    // exp(l_self - m) = 1 counted once
  for (int e = beg + slot; e < end; e += 8) {
    int s = col_src[e];
    float l = a_src[s * HEADS + head1] + adst1;
    l = (l > 0.f) ? l : NEG_SLOPE * l;
    float nm = fmaxf(m, l);
    ssum = ssum * __expf(m - nm) + __expf(l - nm);
    m = nm;
  }
#pragma unroll
  for (int off = 8; off < 64; off <<= 1) {
    float om = __shfl_xor(m, off);
    float os = __shfl_xor(ssum, off);
    float nm = fmaxf(m, om);
    ssum = ssum * __expf(m - nm) + os * __expf(om - nm);
    m = nm;
  }

  // ---- phase 2: weighted bf16 gather (lane owns dims [4*lane,4*lane+4)) ----
  int head2 = lane >> 3;
  float m2 = __shfl(m, head2);
  float inv = 1.f / __shfl(ssum, head2);
  float adst2 = a_dst[node * HEADS + head2];

  auto ew = [&](int s) -> float {
    float l = a_src[s * HEADS + head2] + adst2;
    l = (l > 0.f) ? l : NEG_SLOPE * l;
    return __expf(l - m2);
  };

  float4 acc;
  {
    float w = ew(node);
    us4 hv = *(const us4*)&hb[(size_t)node * OUT_DIM + lane * 4];
    acc.x = w * b2f(hv[0]); acc.y = w * b2f(hv[1]);
    acc.z = w * b2f(hv[2]); acc.w = w * b2f(hv[3]);
  }
  int e = beg;
  for (; e + 4 <= end; e += 4) {
    int s0 = col_src[e], s1 = col_src[e + 1], s2 = col_src[e + 2], s3 = col_src[e + 3];
    float w0 = ew(s0), w1 = ew(s1), w2 = ew(s2), w3 = ew(s3);
    us4 v0 = *(const us4*)&hb[(size_t)s0 * OUT_DIM + lane * 4];
    us4 v1 = *(const us4*)&hb[(size_t)s1 * OUT_DIM + lane * 4];
    us4 v2 = *(const us4*)&hb[(size_t)s2 * OUT_DIM + lane * 4];
    us4 v3 = *(const us4*)&hb[(size_t)s3 * OUT_DIM + lane * 4];
    acc.x += w0 * b2f(v0[0]) + w1 * b2f(v1[0]) + w2 * b2f(v2[0]) + w3 * b2f(v3[0]);
    acc.y += w0 * b2f(v0[1]) + w1 * b2f(v1[1]) + w2 * b2f(v2[1]) + w3 * b2f(v3[1]);
    acc.z += w0 * b2f(v0[2]) + w1 * b2f(v1[2]) + w2 * b2f(v2[2]) + w3 * b2f(v3[2]);
    acc.w += w0 * b2f(v0[3]) + w1 * b2f(v1[3]) + w2 * b2f(v2[3]) + w3 * b2f(v3[3]);
  }
  for (; e < end; ++e) {
    int s = col_src[e];
    float w = ew(s);
    us4 hv = *(const us4*)&hb[(size_t)s * OUT_DIM + lane * 4];
    acc.x += w * b2f(hv[0]); acc.y += w * b2f(hv[1]);
    acc.z += w * b2f(hv[2]); acc.w += w * b2f(hv[3]);
  }
  acc.x *= inv; acc.y *= inv; acc.z *= inv; acc.w *= inv;

  // ---- epilogue: + bias, LayerNorm, gamma/beta ----
  float4 b4 = *(const float4*)&bias[lane * 4];
  acc.x += b4.x; acc.y += b4.y; acc.z += b4.z; acc.w += b4.w;

  float s1 = acc.x + acc.y + acc.z + acc.w;
#pragma unroll
  for (int off = 1; off < 64; off <<= 1) s1 += __shfl_xor(s1, off);
  float mean = s1 * (1.f / OUT_DIM);

  float4 c = make_float4(acc.x - mean, acc.y - mean, acc.z - mean, acc.w - mean);
  float s2 = c.x * c.x + c.y * c.y + c.z * c.z + c.w * c.w;
#pragma unroll
  for (int off = 1; off < 64; off <<= 1) s2 += __shfl_xor(s2, off);
  float rstd = rsqrtf(s2 * (1.f / OUT_DIM) + LN_EPS);

  float4 g4 = *(const float4*)&gamma[lane * 4];
  float4 e4 = *(const float4*)&beta[lane * 4];
  float4 o;
  o.x = c.x * rstd * g4.x + e4.x;
  o.y = c.y * rstd * g4.y + e4.y;
  o.z = c.z * rstd * g4.z + e4.z;
  o.w = c.w * rstd * g4.w + e4.w;
  *(float4*)&out[(size_t)node * OUT_DIM + lane * 4] = o;
}

// ---------------------------------------------------------------------------
extern "C" void kernel_launch(void* const* d_in, const int* in_sizes, int n_in,
                              void* d_out, int out_size, void* d_ws, size_t ws_size,
                              hipStream_t stream) {
  const float* x       = (const float*)d_in[0];
  const int*   ei      = (const int*)d_in[1];
  const float* W       = (const float*)d_in[2];
  const float* att_src = (const float*)d_in[3];
  const float* att_dst = (const float*)d_in[4];
  const float* bias    = (const float*)d_in[5];
  const float* gamma   = (const float*)d_in[6];
  const float* beta    = (const float*)d_in[7];
  float* out = (float*)d_out;

  const int M = in_sizes[0] / IN_DIM;   // 30000
  const int E = in_sizes[1] / 2;        // 480000
  const int NB = (M + 255) / 256;       // 118

  char* w = (char*)d_ws;
  auto carve = [&](size_t bytes) {
    char* p = w;
    w += (bytes + 255) & ~(size_t)255;
    return p;
  };
  unsigned short* xb  = (unsigned short*)carve((size_t)M * IN_DIM * 2);
  unsigned short* Wt  = (unsigned short*)carve((size_t)IN_DIM * OUT_DIM * 2);
  unsigned short* hb  = (unsigned short*)carve((size_t)M * OUT_DIM * 2);
  float* a_srcP = (float*)carve((size_t)M * HEADS * 4);
  float* a_dstP = (float*)carve((size_t)M * HEADS * 4);
  int* row_st   = (int*)carve((size_t)(M + 1) * 4);
  int* cursor   = (int*)carve((size_t)M * 4);
  int* counts   = (int*)carve((size_t)M * 4);
  int* bsum     = (int*)carve((size_t)NB * 4);
  int* bofs     = (int*)carve((size_t)NB * 4);
  int* col_src  = (int*)carve((size_t)E * 4);

  hipMemsetAsync(counts, 0, (size_t)M * 4, stream);

  convert_x<<<(M * (IN_DIM / 8) + 255) / 256, 256, 0, stream>>>(x, xb, M * (IN_DIM / 8));
  convert_wt<<<(IN_DIM * OUT_DIM) / 256, 256, 0, stream>>>(W, Wt);
  count_kernel<<<(E + 255) / 256, 256, 0, stream>>>(ei, counts, E);

  gemm_bf16<<<dim3(OUT_DIM / BN, (M + BM - 1) / BM), 256, 0, stream>>>(xb, Wt, hb, M);

  block_sums<<<NB, 256, 0, stream>>>(counts, bsum, M);
  scan_sums<<<1, 128, 0, stream>>>(bsum, bofs, row_st, NB, M);
  scan_final<<<NB, 256, 0, stream>>>(counts, bofs, row_st, cursor, M);

  attdots_kernel<<<(M * HEADS + 255) / 256, 256, 0, stream>>>(hb, att_src, att_dst,
                                                              a_srcP, a_dstP, M);
  scatter_kernel<<<(E + 255) / 256, 256, 0, stream>>>(ei, cursor, col_src, E);

  aggregate_kernel<<<(M + 3) / 4, 256, 0, stream>>>(hb, a_srcP, a_dstP, row_st, col_src,
                                                    bias, gamma, beta, out, M);
}